// Round 1
// baseline (407.079 us; speedup 1.0000x reference)
//
#include <hip/hip_runtime.h>

// Problem constants (fixed shape from reference): x is (32, 2048, 512) fp32.
#define B_   32
#define T_   2048
#define C_   512
#define S_   (B_ * C_)          // 16384 independent series
#define NC_  64                 // chunks along time
#define L_   (T_ / NC_)         // 32 steps per chunk
#define NQ_  (S_ / 4)           // 4096 float4 "series quads"
#define TOTAL_ ((size_t)B_ * T_ * C_)   // 33554432 elements per output

// ---- constexpr 2x2 matrix power (double precision, compile-time) ----------
struct M2 { double m00, m01, m10, m11; };
constexpr M2 mmul(M2 a, M2 b) {
  return { a.m00*b.m00 + a.m01*b.m10, a.m00*b.m01 + a.m01*b.m11,
           a.m10*b.m00 + a.m11*b.m10, a.m10*b.m01 + a.m11*b.m11 };
}
constexpr M2 mpow(M2 a, int n) {
  M2 r{1.0, 0.0, 0.0, 1.0};
  for (int i = 0; i < n; ++i) r = mmul(r, a);
  return r;
}
constexpr double dALPHA = 0.3, dBETA = 0.3;
// state_t = M * state_{t-1} + (alpha, alpha*beta) * x_t
constexpr M2 M1{1.0 - dALPHA, 1.0 - dALPHA,
                -dALPHA * dBETA, dBETA * (1.0 - dALPHA) + (1.0 - dBETA)};
constexpr M2 ML = mpow(M1, L_);
constexpr float ML00 = (float)ML.m00, ML01 = (float)ML.m01;
constexpr float ML10 = (float)ML.m10, ML11 = (float)ML.m11;

// ---- recurrence step (matches reference arithmetic, linear in s,b,x) ------
__device__ __forceinline__ void step1(float& s, float& b, float x) {
  const float A = 0.3f, Bt = 0.3f;
  float sp = s;
  s = A * x + (1.0f - A) * (sp + b);
  b = Bt * (s - sp) + (1.0f - Bt) * b;
}
__device__ __forceinline__ void step4(float4& s, float4& b, const float4 x) {
  step1(s.x, b.x, x.x);
  step1(s.y, b.y, x.y);
  step1(s.z, b.z, x.z);
  step1(s.w, b.w, x.w);
}

// ---- pass 1: per-chunk linear contribution (chunk 0: exact end state) -----
__global__ __launch_bounds__(256) void dema_pass1(const float* __restrict__ x,
                                                  float* __restrict__ stA) {
  int tid = blockIdx.x * 256 + threadIdx.x;     // NC_ * NQ_ threads
  int j = tid >> 12;                            // chunk (uniform per block)
  int q = tid & (NQ_ - 1);
  int b = q >> 7;                               // C_/4 = 128 quads per batch row
  int c = (q & 127) << 2;
  const float4* xp = reinterpret_cast<const float4*>(
      x + ((size_t)b * T_ + (size_t)j * L_) * C_ + c);
  const int STRD = C_ / 4;                      // 128 float4s between timesteps

  float4 s, bb;
  if (j == 0) {
    float4 x0 = xp[0];
    float4 x1 = xp[STRD];
    s = x0;
    bb = make_float4(x1.x - x0.x, x1.y - x0.y, x1.z - x0.z, x1.w - x0.w);
    // steps t = 1..L_-1 (first scan step consumes x1 again, per reference)
    #pragma unroll 4
    for (int t = 1; t < L_; ++t) {
      float4 xt = xp[(size_t)t * STRD];
      step4(s, bb, xt);
    }
  } else {
    s = make_float4(0.f, 0.f, 0.f, 0.f);
    bb = make_float4(0.f, 0.f, 0.f, 0.f);
    #pragma unroll 4
    for (int t = 0; t < L_; ++t) {
      float4 xt = xp[(size_t)t * STRD];
      step4(s, bb, xt);
    }
  }
  // interleaved (s,b) pairs per series, [chunk][series] layout, float2 each
  float* o = stA + 2 * ((size_t)j * S_ + (size_t)b * C_ + c);
  float4* o4 = reinterpret_cast<float4*>(o);
  o4[0] = make_float4(s.x, bb.x, s.y, bb.y);
  o4[1] = make_float4(s.z, bb.z, s.w, bb.w);
}

// ---- pass 2: sequential combine over chunks; write incoming state per chunk
__global__ __launch_bounds__(256) void dema_pass2(const float2* __restrict__ stA,
                                                  float2* __restrict__ stB) {
  int sid = blockIdx.x * 256 + threadIdx.x;     // S_ threads
  float2 run = stA[sid];                        // exact state at end of chunk 0
  #pragma unroll 8
  for (int j = 1; j < NC_; ++j) {
    float2 v = stA[(size_t)j * S_ + sid];
    stB[(size_t)j * S_ + sid] = run;            // incoming state for chunk j
    float ns = ML00 * run.x + ML01 * run.y + v.x;
    float nb = ML10 * run.x + ML11 * run.y + v.y;
    run.x = ns; run.y = nb;
  }
}

// ---- pass 3: replay each chunk from its incoming state; write res & ma ----
__global__ __launch_bounds__(256) void dema_pass3(const float* __restrict__ x,
                                                  const float2* __restrict__ stB,
                                                  float* __restrict__ out) {
  int tid = blockIdx.x * 256 + threadIdx.x;
  int j = tid >> 12;
  int q = tid & (NQ_ - 1);
  int b = q >> 7;
  int c = (q & 127) << 2;
  size_t base = ((size_t)b * T_ + (size_t)j * L_) * C_ + c;
  const float4* xp = reinterpret_cast<const float4*>(x + base);
  float4* resp = reinterpret_cast<float4*>(out + base);
  float4* map  = reinterpret_cast<float4*>(out + TOTAL_ + base);
  const int STRD = C_ / 4;

  float4 s, bb;
  int tstart;
  if (j == 0) {
    float4 x0 = xp[0];
    float4 x1 = xp[STRD];
    s = x0;
    bb = make_float4(x1.x - x0.x, x1.y - x0.y, x1.z - x0.z, x1.w - x0.w);
    map[0]  = s;                                   // ma[0] = s0
    resp[0] = make_float4(0.f, 0.f, 0.f, 0.f);     // x0 - s0 == 0 exactly
    tstart = 1;
  } else {
    const float4* st = reinterpret_cast<const float4*>(
        stB + (size_t)j * S_ + (size_t)b * C_ + c);
    float4 p0 = st[0];
    float4 p1 = st[1];
    s  = make_float4(p0.x, p0.z, p1.x, p1.z);
    bb = make_float4(p0.y, p0.w, p1.y, p1.w);
    tstart = 0;
  }
  #pragma unroll 4
  for (int t = tstart; t < L_; ++t) {
    float4 xt = xp[(size_t)t * STRD];
    step4(s, bb, xt);
    map[(size_t)t * STRD] = s;
    resp[(size_t)t * STRD] =
        make_float4(xt.x - s.x, xt.y - s.y, xt.z - s.z, xt.w - s.w);
  }
}

extern "C" void kernel_launch(void* const* d_in, const int* in_sizes, int n_in,
                              void* d_out, int out_size, void* d_ws, size_t ws_size,
                              hipStream_t stream) {
  const float* x = (const float*)d_in[0];
  float* out = (float*)d_out;
  // scratch: stA (contributions) and stB (incoming states), 8 MB each
  float2* stA = (float2*)d_ws;
  float2* stB = stA + (size_t)NC_ * S_;

  dema_pass1<<<dim3(NC_ * NQ_ / 256), dim3(256), 0, stream>>>(x, (float*)stA);
  dema_pass2<<<dim3(S_ / 256), dim3(256), 0, stream>>>(stA, stB);
  dema_pass3<<<dim3(NC_ * NQ_ / 256), dim3(256), 0, stream>>>(x, stB, out);
}